// Round 5
// baseline (2454.827 us; speedup 1.0000x reference)
//
#include <hip/hip_runtime.h>
#include <cstdint>
#include <cstddef>

// SimpleRNN on MI355X.
// Outputs (fp32, concatenated): out0 output_tensor (512,64,256), out1 input_proj (64,512,1024),
// out2 tot_rnnhid (64,512,1024), out3 tot_output (64,512,256).
// Pipeline: poison (bf16 +inf sentinel into out0/out3) -> prep (transpose Win/Wout to bf16)
//  -> input_proj GEMM (out1) -> persistent scan (256 WGs = 1/CU, Wr bf16 in VGPR B-frags,
//  DATA-AS-FLAG sync, y-history bf16 in out0/out3) -> output GEMM (out0/out3).
// History:
//  R3: agent-atomic flags, no fences: scan 7.1ms -> 2.47ms.
//  R4/R5 XCD-local L2 sync (plain store + sc0 load): FAILED (flags never visible) -> abandoned.
//  R6 (=R4 bench): DATA-AS-FLAG at L3: poll y dwords vs 0x7F80 sentinel; producers never
//   wait. scan 2.47 -> 1.67ms (3.25us/step). Still latency-bound (MfmaUtil 6.5%).
//  R7 (this round): shorten each hop of the same protocol:
//   - poll via 2x dwordx4 (contiguous per-thread staging; 4x fewer L3 messages, one vmcnt);
//     sentinel check = dword==SENT2 (dword written atomically by one producer store);
//   - producers pack col-pairs via shfl_xor(1), even lanes store dwords (half the messages);
//   - ip prefetched one step ahead (latency hides inside first poll miss);
//   - y_lds double-buffered by step parity -> end-of-step barrier removed (1 barrier/step).

typedef short bf16x8 __attribute__((ext_vector_type(8)));
typedef float f32x4  __attribute__((ext_vector_type(4)));
typedef int   int4v  __attribute__((ext_vector_type(4)));

#define O1_OFF 8388608UL
#define O2_OFF 41943040UL
#define O3_OFF 75497472UL

#define SENT  0x7F80           // bf16 +inf: impossible for tanh output
#define SENT2 0x7F807F80

__device__ __forceinline__ unsigned short f2bf(float f) {
    unsigned u = __float_as_uint(f);
    u += 0x7FFFu + ((u >> 16) & 1u);   // round-to-nearest-even
    return (unsigned short)(u >> 16);
}

// tanh(x) = 1 - 2/(1+exp2(2*log2(e)*x)); ~1e-6 rel err, far below bf16 quantum.
__device__ __forceinline__ float fast_tanh(float x) {
    float e = __builtin_amdgcn_exp2f(2.8853900817779268f * x);
    return 1.0f - 2.0f * __builtin_amdgcn_rcpf(e + 1.0f);
}

// ---------------------------------------------------------------------------
// Poison: fill out0 and out3 (each 33.55MB = exactly the 256-step y regions) with
// the bf16 +inf sentinel. Visibility to the scan via kernel-boundary ordering.
// ---------------------------------------------------------------------------
__global__ void poison_y(int* __restrict__ o0, int* __restrict__ o3)
{
    const int flat = blockIdx.x * 256 + threadIdx.x;        // 0..524287
    int4v p = {SENT2, SENT2, SENT2, SENT2};
#pragma unroll
    for (int c = 0; c < 4; ++c) {
        size_t off = (size_t)c * 2097152 + (size_t)flat * 4;   // dword offset
        __builtin_nontemporal_store(p, (int4v*)(o0 + off));
        __builtin_nontemporal_store(p, (int4v*)(o3 + off));
    }
}

// ---------------------------------------------------------------------------
// Prep: Win (256k x 1024n) -> winT bf16 [1024n][256k];  Wout (1024k x 256n) -> woutT bf16 [256n][1024k]
// ---------------------------------------------------------------------------
__global__ void prep_transpose(const float* __restrict__ Win, const float* __restrict__ Wout,
                               unsigned short* __restrict__ winT, unsigned short* __restrict__ woutT)
{
    __shared__ float tbuf[64 * 65];
    const int tid = threadIdx.x;
    const int bx = blockIdx.x;
    const float* src; unsigned short* dst; int k0, n0, srcld, dstld;
    if (bx < 64) { int tk = bx & 3, tn = bx >> 2; k0 = tk * 64; n0 = tn * 64; src = Win;  srcld = 1024; dst = winT;  dstld = 256; }
    else         { int b2 = bx - 64; int tk = b2 >> 2, tn = b2 & 3; k0 = tk * 64; n0 = tn * 64; src = Wout; srcld = 256;  dst = woutT; dstld = 1024; }

    for (int it = 0; it < 16; ++it) {
        int flat = it * 256 + tid;
        int k = flat >> 6, nn = flat & 63;
        tbuf[k * 65 + nn] = src[(size_t)(k0 + k) * srcld + n0 + nn];
    }
    __syncthreads();
    int* d32 = (int*)dst;
    for (int it = 0; it < 8; ++it) {
        int flat = it * 256 + tid;            // 0..2047
        int nn = flat >> 5, kd = flat & 31;   // kd = k-pair index
        float v0 = tbuf[(2 * kd) * 65 + nn];
        float v1 = tbuf[(2 * kd + 1) * 65 + nn];
        d32[(size_t)(n0 + nn) * (dstld / 2) + (k0 / 2) + kd] = (int)(f2bf(v0) | ((unsigned)f2bf(v1) << 16));
    }
}

// ---------------------------------------------------------------------------
// Phase A: input_proj = x(32768r x 256k) @ Win(256k x 1024n), out1[(b*512+t)*1024+n], r = t*64+b
// ---------------------------------------------------------------------------
__launch_bounds__(256, 1)
__global__ void input_proj_kernel(const float* __restrict__ x, const unsigned short* __restrict__ winT,
                                  float* __restrict__ ip)
{
    extern __shared__ short lds[];
    short* win_s = lds;             // [256 n][264] bf16
    short* x_s   = lds + 256 * 264; // [32 m][264] bf16
    const int tid = threadIdx.x;
    const int lane = tid & 63, wv = tid >> 6;
    const int nslice = blockIdx.x & 3;
    const int wgm = blockIdx.x >> 2;
    const int n0 = nslice * 256;
    const int n = lane & 15, q = lane >> 4;

    { // stage WinT slice, coalesced + conflict-free
        const int* src = (const int*)winT;   // [1024][128 dwords]
        int* dstl = (int*)win_s;             // pitch 132 dwords
        for (int it = 0; it < 128; ++it) {
            int flat = it * 256 + tid;
            int nn = flat >> 7, kd = flat & 127;
            dstl[nn * 132 + kd] = src[(size_t)(n0 + nn) * 128 + kd];
        }
    }
    __syncthreads();

    const int msub = (wv & 1) * 16;
    const int ntbase = (wv >> 1) * 8;

    for (int i = 0; i < 16; ++i) {
        int mt = wgm * 16 + i;
        int r0 = mt * 32;
        { // stage x tile 32x256 fp32 -> bf16
            for (int it = 0; it < 16; ++it) {
                int flat = it * 256 + tid;     // 0..4095
                int rr = flat >> 7, kp = flat & 127;
                const float* xp = x + (size_t)(r0 + rr) * 256 + kp * 2;
                ((int*)x_s)[rr * 132 + kp] = (int)(f2bf(xp[0]) | ((unsigned)f2bf(xp[1]) << 16));
            }
        }
        __syncthreads();

        f32x4 acc[8] = {};
#pragma unroll
        for (int kc = 0; kc < 8; ++kc) {
            bf16x8 af = *(const bf16x8*)(x_s + (msub + n) * 264 + kc * 32 + q * 8);
#pragma unroll
            for (int u = 0; u < 8; ++u) {
                bf16x8 bfv = *(const bf16x8*)(win_s + ((ntbase + u) * 16 + n) * 264 + kc * 32 + q * 8);
                acc[u] = __builtin_amdgcn_mfma_f32_16x16x32_bf16(af, bfv, acc[u], 0, 0, 0);
            }
        }
#pragma unroll
        for (int u = 0; u < 8; ++u) {
            int ncol = n0 + (ntbase + u) * 16 + n;
#pragma unroll
            for (int rr = 0; rr < 4; ++rr) {
                int R = r0 + msub + q * 4 + rr;
                int t = R >> 6, b = R & 63;
                ip[((size_t)b * 512 + t) * 1024 + ncol] = acc[u][rr];
            }
        }
        __syncthreads();
    }
}

// ---------------------------------------------------------------------------
// Persistent scan. 256 WGs x 256 thr (plain launch; 1 WG/CU => all co-resident).
// group g = 4 batches, 16 WGs/group x 64 cols. Wave = 16 cols; Wr bf16 B-frags in VGPRs.
// DATA-AS-FLAG: thread (r = tid>>6, c8 = (tid&63)*8) polls its 8 CONTIGUOUS dwords of
// y_{t-1}[b0+r][*] via 2x global_load_dwordx4 (sc0 sc1 = coherent at L3) until none equal
// SENT2; each dword is written atomically by one producer dword-store, so dword!=SENT2
// <=> valid. Producers pack col-pairs via shfl_xor(1); even lanes store dwords; NO waits.
// y_lds double-buffered by step parity => single barrier per step (stage -> MFMA read).
// Sticky watchdog: a trip stages +inf -> NaN absmax (visible failure, never a hang).
// ---------------------------------------------------------------------------
__launch_bounds__(256, 1)
__global__ void rnn_scan(const float* __restrict__ Wr, const float* __restrict__ bias,
                         const float* __restrict__ ip, float* __restrict__ hout,
                         char* ybase0, char* ybase3)
{
    __shared__ int y_lds[2][4][516];   // [parity][row][512 dwords + pad]
    const int tid = threadIdx.x;
    const int lane = tid & 63;
    const int bx = blockIdx.x;
    const int j = bx >> 3;                  // 0..31
    const int g = (bx & 7) + 8 * (j & 1);   // group 0..15 (XCD-affine locality)
    const int w = j >> 1;                   // slice 0..15
    const int b0 = g * 4;
    const int colbase = w * 64 + (tid >> 6) * 16;
    const int n = lane & 15;                // col within tile; also A-frag row index
    const int q = lane >> 4;
    const int col = colbase + n;

    // Load Wr B-frags: lane holds Wr[kc*32+q*8+jj][col], bf16
    bf16x8 wrf[32];
#pragma unroll
    for (int kc = 0; kc < 32; ++kc) {
        int kbase = kc * 32 + q * 8;
        union { bf16x8 v; unsigned short u[8]; } tmp;
#pragma unroll
        for (int jj = 0; jj < 8; ++jj)
            tmp.u[jj] = f2bf(Wr[(size_t)(kbase + jj) * 1024 + col]);
        wrf[kc] = tmp.v;
    }
    const float biasv = bias[col];

    float h[4] = {0.f, 0.f, 0.f, 0.f};
    int gaveup = 0;
    const int r  = tid >> 6;          // staging row 0..3
    const int c8 = (tid & 63) * 8;    // staging dword base (8 contiguous dwords)

    // ip prefetch for t=0 (lanes 0-15 hold batches 0-3, C-frag layout)
    float ipv[4] = {0.f, 0.f, 0.f, 0.f};
    if (lane < 16) {
#pragma unroll
        for (int rr = 0; rr < 4; ++rr)
            ipv[rr] = __builtin_nontemporal_load(ip + ((size_t)(b0 + rr) * 512 + 0) * 1024 + col);
    }

    for (int t = 0; t < 512; ++t) {
        f32x4 acc0 = {0.f, 0.f, 0.f, 0.f}, acc1 = {0.f, 0.f, 0.f, 0.f};
        if (t > 0) {
            const int* ysrc = (const int*)((t - 1) < 256 ? (ybase0 + (size_t)(t - 1) * 131072)
                                                         : (ybase3 + (size_t)(t - 1 - 256) * 131072));
            const int* bsrc = ysrc + (b0 + r) * 512 + c8;
            int4v va, vb;
            int spins = 0;
            while (true) {
                asm volatile(
                    "global_load_dwordx4 %0, %2, off sc0 sc1\n\t"
                    "global_load_dwordx4 %1, %2, off offset:16 sc0 sc1\n\t"
                    "s_waitcnt vmcnt(0)"
                    : "=&v"(va), "=&v"(vb) : "v"(bsrc) : "memory");
                bool ok = (va[0] != SENT2) && (va[1] != SENT2) && (va[2] != SENT2) && (va[3] != SENT2)
                       && (vb[0] != SENT2) && (vb[1] != SENT2) && (vb[2] != SENT2) && (vb[3] != SENT2);
                if (ok || gaveup) break;
                if (__builtin_expect(++spins > (1 << 16), 0)) { gaveup = 1; break; }
                if (spins > 8) __builtin_amdgcn_s_sleep(1);
            }
            *(int4v*)&y_lds[t & 1][r][c8]     = va;   // 2x ds_write_b128
            *(int4v*)&y_lds[t & 1][r][c8 + 4] = vb;
            __syncthreads();   // the ONLY barrier per step: stage complete before frag reads

            // MFMA over K=1024: A rows 0-3 = y batches, rows 4-15 zero
            const short* ybuf = (const short*)y_lds[t & 1];
#pragma unroll
            for (int kc = 0; kc < 32; kc += 2) {
                bf16x8 a0, a1;
                if (n < 4) {
                    a0 = *(const bf16x8*)(ybuf + n * 1032 + kc * 32 + q * 8);
                    a1 = *(const bf16x8*)(ybuf + n * 1032 + (kc + 1) * 32 + q * 8);
                } else { a0 = (bf16x8)0; a1 = (bf16x8)0; }
                acc0 = __builtin_amdgcn_mfma_f32_16x16x32_bf16(a0, wrf[kc],     acc0, 0, 0, 0);
                acc1 = __builtin_amdgcn_mfma_f32_16x16x32_bf16(a1, wrf[kc + 1], acc1, 0, 0, 0);
            }
        }

        // h update (lanes>=16 compute phantom rows; never stored, A-rows forced zero so harmless)
#pragma unroll
        for (int rr = 0; rr < 4; ++rr) {
            float rv = acc0[rr] + acc1[rr];
            h[rr] = 0.95f * h[rr] + 0.05f * (rv + ipv[rr] + biasv);
        }

        // y stores: pack col-pairs (this lane + lane^1) into dwords; even lanes store.
        // Consumers wait on these; fire first, never wait.
        {
            char* ydst = (t < 256) ? (ybase0 + (size_t)t * 131072) : (ybase3 + (size_t)(t - 256) * 131072);
            int* ypd = (int*)ydst;
            int mybf[4];
#pragma unroll
            for (int rr = 0; rr < 4; ++rr)
                mybf[rr] = (int)f2bf(fast_tanh(h[rr]));
#pragma unroll
            for (int rr = 0; rr < 4; ++rr) {
                int pbf = __shfl_xor(mybf[rr], 1);
                if (lane < 16 && (n & 1) == 0) {
                    int dv = mybf[rr] | (pbf << 16);
                    __hip_atomic_store(ypd + (b0 + rr) * 512 + (col >> 1), dv,
                                       __ATOMIC_RELAXED, __HIP_MEMORY_SCOPE_AGENT);
                }
            }
        }
        // hout (out2): not on the sync critical path (read only by out_proj kernel)
        if (lane < 16) {
#pragma unroll
            for (int rr = 0; rr < 4; ++rr)
                __builtin_nontemporal_store(h[rr], hout + ((size_t)(b0 + rr) * 512 + t) * 1024 + col);
        }
        // ip prefetch for t+1: latency hides inside the next poll's first miss
        if (t < 511 && lane < 16) {
#pragma unroll
            for (int rr = 0; rr < 4; ++rr)
                ipv[rr] = __builtin_nontemporal_load(ip + ((size_t)(b0 + rr) * 512 + (t + 1)) * 1024 + col);
        }
    }
}

// ---------------------------------------------------------------------------
// Phase C: rnn_out = tanh(out2) (32768r x 1024k) @ Wout -> out3[R*256+n] and out0[(t*64+b)*256+n]
// ---------------------------------------------------------------------------
__launch_bounds__(256, 1)
__global__ void out_proj_kernel(const float* __restrict__ h, const unsigned short* __restrict__ woutT,
                                float* __restrict__ out0, float* __restrict__ out3)
{
    extern __shared__ short lds[];      // [256 n][136] bf16 per k-block
    const int tid = threadIdx.x;
    const int lane = tid & 63, wv = tid >> 6;
    const int R0 = blockIdx.x * 64;
    const int n = lane & 15, q = lane >> 4;
    f32x4 acc[16] = {};

    for (int kb = 0; kb < 8; ++kb) {
        { // stage WoutT block, coalesced + conflict-free
            const int* src = (const int*)woutT;   // [256][512 dwords]
            int* dstl = (int*)lds;                // pitch 68 dwords
#pragma unroll
            for (int it = 0; it < 64; ++it) {
                int flat = it * 256 + tid;
                int nn = flat >> 6, kd = flat & 63;
                dstl[nn * 68 + kd] = src[(size_t)nn * 512 + kb * 64 + kd];
            }
        }
        __syncthreads();

        const int row = R0 + wv * 16 + n;
#pragma unroll
        for (int kc = 0; kc < 4; ++kc) {
            int k = kb * 128 + kc * 32 + q * 8;
            const float* hp = h + (size_t)row * 1024 + k;
            union { bf16x8 v; unsigned short u[8]; } af;
#pragma unroll
            for (int jj = 0; jj < 8; ++jj) af.u[jj] = f2bf(fast_tanh(hp[jj]));
#pragma unroll
            for (int u2 = 0; u2 < 16; ++u2) {
                bf16x8 bfv = *(const bf16x8*)(lds + (u2 * 16 + n) * 136 + kc * 32 + q * 8);
                acc[u2] = __builtin_amdgcn_mfma_f32_16x16x32_bf16(af.v, bfv, acc[u2], 0, 0, 0);
            }
        }
        __syncthreads();
    }
#pragma unroll
    for (int u2 = 0; u2 < 16; ++u2) {
        int ncol = u2 * 16 + n;
#pragma unroll
        for (int rr = 0; rr < 4; ++rr) {
            int R = R0 + wv * 16 + q * 4 + rr;
            int b = R >> 9, t = R & 511;
            float v = acc[u2][rr];
            out3[(size_t)R * 256 + ncol] = v;
            out0[((size_t)t * 64 + b) * 256 + ncol] = v;
        }
    }
}

// ---------------------------------------------------------------------------
extern "C" void kernel_launch(void* const* d_in, const int* in_sizes, int n_in,
                              void* d_out, int out_size, void* d_ws, size_t ws_size,
                              hipStream_t stream)
{
    const float* x    = (const float*)d_in[0];
    const float* Win  = (const float*)d_in[1];
    const float* Wr   = (const float*)d_in[2];
    const float* bias = (const float*)d_in[3];
    const float* Wout = (const float*)d_in[4];
    float* out = (float*)d_out;
    float* o0 = out;
    float* o1 = out + O1_OFF;
    float* o2 = out + O2_OFF;
    float* o3 = out + O3_OFF;

    // ws layout: [0,+512K) winT, then woutT. (No flags: sync is data-as-flag.)
    unsigned short* winT  = (unsigned short*)d_ws;
    unsigned short* woutT = (unsigned short*)((char*)d_ws + 524288);

    hipFuncSetAttribute((const void*)input_proj_kernel, hipFuncAttributeMaxDynamicSharedMemorySize, 152064);
    hipFuncSetAttribute((const void*)out_proj_kernel,   hipFuncAttributeMaxDynamicSharedMemorySize, 69632);

    hipLaunchKernelGGL(poison_y, dim3(2048), dim3(256), 0, stream, (int*)o0, (int*)o3);
    hipLaunchKernelGGL(prep_transpose, dim3(128), dim3(256), 0, stream, Win, Wout, winT, woutT);
    hipLaunchKernelGGL(input_proj_kernel, dim3(256), dim3(256), 152064, stream, x, winT, o1);

    hipLaunchKernelGGL(rnn_scan, dim3(256), dim3(256), 0, stream,
                       Wr, bias, o1, o2, (char*)o0, (char*)o3);

    hipLaunchKernelGGL(out_proj_kernel, dim3(512), dim3(256), 69632, stream, o2, woutT, o0, o3);
}